// Round 13
// baseline (515.934 us; speedup 1.0000x reference)
//
#include <hip/hip_runtime.h>
#include <hip/hip_bf16.h>
#include <math.h>

// ---------------------------------------------------------------------------
// RESKnorm GCN, CSR-based (no float atomics), f32 everywhere.
//   CSR: histogram + 2-dispatch scan + per-node-cursor scatter fill.
//   fill FUSED with lin0 using HALF-COLUMN W tiles (16KB LDS).
//   Aggregation PANELIZED by channel (R13): 4 panels x 16ch; wave=(panel,node),
//   4-lane group per edge, 16 edges/iter. Panel working set = 3.2MB < 4MiB
//   per-XCD L2 -> gathers L2-resident (full-row agg was L3-latency-bound on a
//   12.8MB set). Panel-major block order; nt-loads on the edge-payload stream.
//   lin1/2/3 are standalone again (lin fusion needed the full h row).
// N=50000, E=800000, NFEAT=128, NHID=64, NCLASS=40, GROUPS=32 (2 ch/group)
// ---------------------------------------------------------------------------

#define EPS 1e-5f
#define SCAN_BLK 256

// ---------------- CSR build ----------------
__global__ void count_kernel(const int* __restrict__ tgt, int* __restrict__ cnt,
                             int E) {
    int e = blockIdx.x * blockDim.x + threadIdx.x;
    if (e < E) atomicAdd(&cnt[tgt[e]], 1);
}

__global__ void scan_p1(const int* __restrict__ cnt, int* __restrict__ bsum,
                        int n) {
    __shared__ int lds[SCAN_BLK];
    int i = blockIdx.x * SCAN_BLK + threadIdx.x;
    lds[threadIdx.x] = (i < n) ? cnt[i] : 0;
    __syncthreads();
    for (int off = SCAN_BLK / 2; off; off >>= 1) {
        if (threadIdx.x < off) lds[threadIdx.x] += lds[threadIdx.x + off];
        __syncthreads();
    }
    if (threadIdx.x == 0) bsum[blockIdx.x] = lds[0];
}

__global__ void scan_p23(const int* __restrict__ cnt, const int* __restrict__ bsum,
                         int* __restrict__ rowptr, int* __restrict__ cursor,
                         int n) {
    __shared__ int lds[SCAN_BLK];
    __shared__ int boff_s;
    int p = 0;
    for (int i = threadIdx.x; i < (int)blockIdx.x; i += SCAN_BLK) p += bsum[i];
    lds[threadIdx.x] = p;
    __syncthreads();
    for (int off = SCAN_BLK / 2; off; off >>= 1) {
        if (threadIdx.x < off) lds[threadIdx.x] += lds[threadIdx.x + off];
        __syncthreads();
    }
    if (threadIdx.x == 0) boff_s = lds[0];
    __syncthreads();
    int boff = boff_s;
    __syncthreads();
    int i = blockIdx.x * SCAN_BLK + threadIdx.x;
    int v = (i < n) ? cnt[i] : 0;
    lds[threadIdx.x] = v;
    __syncthreads();
    for (int off = 1; off < SCAN_BLK; off <<= 1) {
        int t = (threadIdx.x >= off) ? lds[threadIdx.x - off] : 0;
        __syncthreads();
        lds[threadIdx.x] += t;
        __syncthreads();
    }
    int excl = boff + lds[threadIdx.x] - v;
    if (i < n) {
        rowptr[i] = excl;
        cursor[i] = excl;
        if (i == n - 1) rowptr[n] = excl + v;
    }
}

// ---------------- fused fill + lin0 (half-column 16KB W tiles) -------------
__global__ void fill_lin0_kernel(const int* __restrict__ src,
                                 const int* __restrict__ tgt,
                                 const float* __restrict__ mv,
                                 int* __restrict__ cursor,
                                 long long* __restrict__ ep, int E,
                                 const float* __restrict__ X,
                                 const float4* __restrict__ W4,   // [128*16]
                                 const float4* __restrict__ B4,   // [16]
                                 float4* __restrict__ S4out, int n,
                                 int fillBlocks, int halfBlocks) {
    __shared__ float4 Wl[128 * 8];
    __shared__ float4 Bl8[8];
    if (blockIdx.x < (unsigned)fillBlocks) {
        int e = blockIdx.x * blockDim.x + threadIdx.x;
        if (e >= E) return;
        int pos = atomicAdd(&cursor[tgt[e]], 1);
        long long v = (long long)(unsigned)src[e] |
                      ((long long)__float_as_int(mv[e]) << 32);
        ep[pos] = v;
        return;
    }
    int t = blockIdx.x - fillBlocks;
    int half = (t >= halfBlocks) ? 1 : 0;
    int bi = t - half * halfBlocks;
    for (int i = threadIdx.x; i < 128 * 8; i += blockDim.x)
        Wl[i] = W4[(i >> 3) * 16 + half * 8 + (i & 7)];
    if (threadIdx.x < 8) Bl8[threadIdx.x] = B4[half * 8 + threadIdx.x];
    __syncthreads();
    int idx = bi * blockDim.x + threadIdx.x;
    if (idx >= n * 8) return;
    int row = idx >> 3;
    int c8 = idx & 7;
    const float* xr = X + (long)row * 128;
    float4 acc = Bl8[c8];
#pragma unroll 8
    for (int k = 0; k < 128; ++k) {
        float xv = xr[k];
        float4 w = Wl[k * 8 + c8];
        acc.x = fmaf(xv, w.x, acc.x);
        acc.y = fmaf(xv, w.y, acc.y);
        acc.z = fmaf(xv, w.z, acc.z);
        acc.w = fmaf(xv, w.w, acc.w);
    }
    S4out[(long)row * 16 + half * 8 + c8] = acc;
}

// ---------------- S = X @ W + b (standalone, layers 1..3) ----------------
template <int K, int COLS>
__global__ void lin_kernel(const float* __restrict__ X, const float* __restrict__ W,
                           const float* __restrict__ B, float* __restrict__ S,
                           int n) {
    constexpr int C4 = COLS / 4;
    __shared__ float4 Wl[K * C4];
    __shared__ float Bl[COLS];
    for (int i = threadIdx.x; i < K * C4; i += blockDim.x)
        Wl[i] = ((const float4*)W)[i];
    for (int i = threadIdx.x; i < COLS; i += blockDim.x) Bl[i] = B[i];
    __syncthreads();
    int idx = blockIdx.x * blockDim.x + threadIdx.x;
    int total = n * C4;
    if (idx >= total) return;
    int row = idx / C4;
    int c4 = idx - row * C4;
    const float* xr = X + (long)row * K;
    float4 acc;
    acc.x = Bl[4 * c4 + 0];
    acc.y = Bl[4 * c4 + 1];
    acc.z = Bl[4 * c4 + 2];
    acc.w = Bl[4 * c4 + 3];
#pragma unroll 4
    for (int k = 0; k < K; ++k) {
        float xv = xr[k];
        float4 w = Wl[k * C4 + c4];
        acc.x = fmaf(xv, w.x, acc.x);
        acc.y = fmaf(xv, w.y, acc.y);
        acc.z = fmaf(xv, w.z, acc.z);
        acc.w = fmaf(xv, w.w, acc.w);
    }
    ((float4*)S)[idx] = acc;
}

#define FMA4(A, V, W4)                                                        \
    A.x = fmaf(V.x, W4, A.x); A.y = fmaf(V.y, W4, A.y);                       \
    A.z = fmaf(V.z, W4, A.z); A.w = fmaf(V.w, W4, A.w);

// ---------------- panelized aggregation (layers 0-2) ----------------
// wave = (panel, node). lane: g=lane>>2 (edge slot 0..15), c=lane&3 (float4
// within the 16ch panel). 16 edges per iteration; 4-stage xor reduce.
// Panel working set = N*64B = 3.2MB -> per-XCD L2 resident. ep loads nt.
#define AGGP_BODY()                                                           \
    int beg = rowptr[node], end = rowptr[node + 1];                           \
    float4 acc = make_float4(0.f, 0.f, 0.f, 0.f);                             \
    for (int j = beg; j < end; j += 16) {                                     \
        int ei = j + g;                                                       \
        bool vld = ei < end;                                                  \
        long long p = __builtin_nontemporal_load(&ep[vld ? ei : end - 1]);    \
        float wv = vld ? __int_as_float((int)(p >> 32)) : 0.f;                \
        float4 s = S4[(long)(int)(unsigned)p * 16 + pb + c];                  \
        FMA4(acc, s, wv)                                                      \
    }                                                                         \
    acc.x += __shfl_xor(acc.x, 4);  acc.y += __shfl_xor(acc.y, 4);            \
    acc.z += __shfl_xor(acc.z, 4);  acc.w += __shfl_xor(acc.w, 4);            \
    acc.x += __shfl_xor(acc.x, 8);  acc.y += __shfl_xor(acc.y, 8);            \
    acc.z += __shfl_xor(acc.z, 8);  acc.w += __shfl_xor(acc.w, 8);            \
    acc.x += __shfl_xor(acc.x, 16); acc.y += __shfl_xor(acc.y, 16);           \
    acc.z += __shfl_xor(acc.z, 16); acc.w += __shfl_xor(acc.w, 16);           \
    acc.x += __shfl_xor(acc.x, 32); acc.y += __shfl_xor(acc.y, 32);           \
    acc.z += __shfl_xor(acc.z, 32); acc.w += __shfl_xor(acc.w, 32);

// layer 0: H[node, panel] = relu(agg)
__global__ void aggp_relu_kernel(const float4* __restrict__ S4,
                                 const int* __restrict__ rowptr,
                                 const long long* __restrict__ ep,
                                 float4* __restrict__ H4, int n) {
    int gwid = (blockIdx.x * blockDim.x + threadIdx.x) >> 6;
    if (gwid >= 4 * n) return;
    int lane = threadIdx.x & 63;
    int panel = gwid / n;
    int node = gwid - panel * n;
    int g = lane >> 2, c = lane & 3;
    int pb = panel * 4;
    AGGP_BODY()
    if (g != 0) return;
    H4[(long)node * 16 + pb + c] =
        make_float4(fmaxf(acc.x, 0.f), fmaxf(acc.y, 0.f),
                    fmaxf(acc.z, 0.f), fmaxf(acc.w, 0.f));
}

// layers 1-2: H[node, panel] += gn(relu(agg)) (pairs (x,y),(z,w) lane-local)
__global__ void aggp_gn_kernel(const float4* __restrict__ S4,
                               const int* __restrict__ rowptr,
                               const long long* __restrict__ ep,
                               const float4* __restrict__ gamma,
                               const float4* __restrict__ beta,
                               float4* __restrict__ H4, int n) {
    int gwid = (blockIdx.x * blockDim.x + threadIdx.x) >> 6;
    if (gwid >= 4 * n) return;
    int lane = threadIdx.x & 63;
    int panel = gwid / n;
    int node = gwid - panel * n;
    int g = lane >> 2, c = lane & 3;
    int pb = panel * 4;
    AGGP_BODY()
    if (g != 0) return;
    float p0 = fmaxf(acc.x, 0.f), p1 = fmaxf(acc.y, 0.f);
    float p2 = fmaxf(acc.z, 0.f), p3 = fmaxf(acc.w, 0.f);
    float dA = 0.5f * (p0 - p1);
    float dB = 0.5f * (p2 - p3);
    float rsA = rsqrtf(dA * dA + EPS);
    float rsB = rsqrtf(dB * dB + EPS);
    float4 gm = gamma[pb + c], be = beta[pb + c];
    long off = (long)node * 16 + pb + c;
    float4 h = H4[off];
    h.x += dA * rsA * gm.x + be.x;
    h.y += -dA * rsA * gm.y + be.y;
    h.z += dB * rsB * gm.z + be.z;
    h.w += -dB * rsB * gm.w + be.w;
    H4[off] = h;
}

// ---------------- layer 3: full-row agg + log_softmax (unchanged) ----------
#define AGG4_BODY(R4)                                                         \
    int beg = rowptr[wid], end = rowptr[wid + 1];                             \
    float4 a0 = make_float4(0.f, 0.f, 0.f, 0.f), a1 = a0, a2 = a0, a3 = a0;   \
    int j = beg;                                                              \
    for (; j + 16 <= end; j += 16) {                                          \
        long long p0 = ep[j + q], p1 = ep[j + 4 + q];                         \
        long long p2 = ep[j + 8 + q], p3 = ep[j + 12 + q];                    \
        float4 v0 = S4[(long)(int)(unsigned)p0 * R4 + sub];                   \
        float4 v1 = S4[(long)(int)(unsigned)p1 * R4 + sub];                   \
        float4 v2 = S4[(long)(int)(unsigned)p2 * R4 + sub];                   \
        float4 v3 = S4[(long)(int)(unsigned)p3 * R4 + sub];                   \
        float w0 = __int_as_float((int)(p0 >> 32));                           \
        float w1 = __int_as_float((int)(p1 >> 32));                           \
        float w2 = __int_as_float((int)(p2 >> 32));                           \
        float w3 = __int_as_float((int)(p3 >> 32));                           \
        FMA4(a0, v0, w0) FMA4(a1, v1, w1) FMA4(a2, v2, w2) FMA4(a3, v3, w3)   \
    }                                                                         \
    for (; j + 4 <= end; j += 4) {                                            \
        long long p0 = ep[j + q];                                             \
        float4 v0 = S4[(long)(int)(unsigned)p0 * R4 + sub];                   \
        float w0 = __int_as_float((int)(p0 >> 32));                           \
        FMA4(a0, v0, w0)                                                      \
    }                                                                         \
    if (j < end) {                                                            \
        int eidx = j + q;                                                     \
        long long p0 = ep[(eidx < end) ? eidx : (end - 1)];                   \
        float4 v0 = S4[(long)(int)(unsigned)p0 * R4 + sub];                   \
        float w0 = (eidx < end) ? __int_as_float((int)(p0 >> 32)) : 0.f;      \
        FMA4(a0, v0, w0)                                                      \
    }                                                                         \
    float4 acc;                                                               \
    acc.x = (a0.x + a1.x) + (a2.x + a3.x);                                    \
    acc.y = (a0.y + a1.y) + (a2.y + a3.y);                                    \
    acc.z = (a0.z + a1.z) + (a2.z + a3.z);                                    \
    acc.w = (a0.w + a1.w) + (a2.w + a3.w);                                    \
    acc.x += __shfl_xor(acc.x, 16); acc.y += __shfl_xor(acc.y, 16);           \
    acc.z += __shfl_xor(acc.z, 16); acc.w += __shfl_xor(acc.w, 16);           \
    acc.x += __shfl_xor(acc.x, 32); acc.y += __shfl_xor(acc.y, 32);           \
    acc.z += __shfl_xor(acc.z, 32); acc.w += __shfl_xor(acc.w, 32);

__global__ void agg_lsm_kernel(const float4* __restrict__ S4,
                               const int* __restrict__ rowptr,
                               const long long* __restrict__ ep,
                               float4* __restrict__ out4, int n) {
    int wid = (blockIdx.x * blockDim.x + threadIdx.x) >> 6;
    int lane = threadIdx.x & 63;
    int q = lane >> 4;
    int sub0 = lane & 15;
    int sub = (sub0 < 10) ? sub0 : 9;  // clamp: in-bounds dup loads, ignored
    if (wid >= n) return;
    AGG4_BODY(10)
    bool valid = sub0 < 10;
    float m = valid ? fmaxf(fmaxf(acc.x, acc.y), fmaxf(acc.z, acc.w)) : -INFINITY;
#pragma unroll
    for (int mk = 8; mk; mk >>= 1) m = fmaxf(m, __shfl_xor(m, mk));
    float ex = valid ? (expf(acc.x - m) + expf(acc.y - m) +
                        expf(acc.z - m) + expf(acc.w - m)) : 0.f;
#pragma unroll
    for (int mk = 8; mk; mk >>= 1) ex += __shfl_xor(ex, mk);
    float l = m + logf(ex);
    if (q == 0 && valid)
        out4[(long)wid * 10 + sub0] =
            make_float4(acc.x - l, acc.y - l, acc.z - l, acc.w - l);
}

extern "C" void kernel_launch(void* const* d_in, const int* in_sizes, int n_in,
                              void* d_out, int out_size, void* d_ws,
                              size_t ws_size, hipStream_t stream) {
    const float* x = (const float*)d_in[0];
    const int* src = (const int*)d_in[1];
    const int* tgt = (const int*)d_in[2];
    const float* mv = (const float*)d_in[3];
    const float* W0 = (const float*)d_in[4];
    const float* b0 = (const float*)d_in[5];
    const float* W1 = (const float*)d_in[6];
    const float* b1 = (const float*)d_in[7];
    const float* W2 = (const float*)d_in[8];
    const float* b2 = (const float*)d_in[9];
    const float* W3 = (const float*)d_in[10];
    const float* b3 = (const float*)d_in[11];
    const float* g1 = (const float*)d_in[12];
    const float* beta1 = (const float*)d_in[13];
    const float* g2 = (const float*)d_in[14];
    const float* beta2 = (const float*)d_in[15];

    const int N = in_sizes[0] / 128;
    const int E = in_sizes[1];

    float* buf_s0 = (float*)d_ws;               // [N,64] S ping
    float* buf_s1 = buf_s0 + (size_t)N * 64;    // [N,64] S pong
    float* buf_h = buf_s1 + (size_t)N * 64;     // [N,64] h / residual
    int* rowptr = (int*)(buf_h + (size_t)N * 64);  // [N+1]
    int* cursor = rowptr + (N + 1);             // [N]
    int* cnt = cursor + N;                      // [N]
    int* bsum = cnt + N;                        // [<=1024]
    long long* epack = (long long*)(((uintptr_t)(bsum + 1024) + 15) & ~(uintptr_t)15);

    const int BLK = 256;
    auto grid = [](long total, int blk) { return (int)((total + blk - 1) / blk); };
    const int scanBlocks = grid(N, SCAN_BLK);
    const int fillBlocks = grid(E, BLK);
    const int halfBlocks = grid((long)N * 8, BLK);

    // ---- CSR build ----
    hipMemsetAsync(cnt, 0, (size_t)N * sizeof(int), stream);
    count_kernel<<<grid(E, BLK), BLK, 0, stream>>>(tgt, cnt, E);
    scan_p1<<<scanBlocks, SCAN_BLK, 0, stream>>>(cnt, bsum, N);
    scan_p23<<<scanBlocks, SCAN_BLK, 0, stream>>>(cnt, bsum, rowptr, cursor, N);

    // ---- fused: CSR fill + layer-0 linear (half-tile LDS) -> S0 ----
    fill_lin0_kernel<<<fillBlocks + 2 * halfBlocks, BLK, 0, stream>>>(
        src, tgt, mv, cursor, epack, E, x, (const float4*)W0, (const float4*)b0,
        (float4*)buf_s0, N, fillBlocks, halfBlocks);

    const int aggpBlocks = grid((long)N * 4 * 64, BLK);  // wave per (panel,node)
    const int aggBlocks = grid((long)N * 64, BLK);

    // ---- layer 0: H = relu(agg(S0)) [panelized] ----
    aggp_relu_kernel<<<aggpBlocks, BLK, 0, stream>>>(
        (const float4*)buf_s0, rowptr, epack, (float4*)buf_h, N);

    // ---- lin1: S1 = H@W1+b1 ----
    lin_kernel<64, 64><<<grid((long)N * 16, BLK), BLK, 0, stream>>>(buf_h, W1, b1, buf_s1, N);

    // ---- layer 1: H += gn(relu(agg(S1))) [panelized] ----
    aggp_gn_kernel<<<aggpBlocks, BLK, 0, stream>>>(
        (const float4*)buf_s1, rowptr, epack, (const float4*)g1,
        (const float4*)beta1, (float4*)buf_h, N);

    // ---- lin2: S0 = H@W2+b2 ----
    lin_kernel<64, 64><<<grid((long)N * 16, BLK), BLK, 0, stream>>>(buf_h, W2, b2, buf_s0, N);

    // ---- layer 2: H += gn(relu(agg(S0))) [panelized] ----
    aggp_gn_kernel<<<aggpBlocks, BLK, 0, stream>>>(
        (const float4*)buf_s0, rowptr, epack, (const float4*)g2,
        (const float4*)beta2, (float4*)buf_h, N);

    // ---- lin3: S1 = H@W3+b3 as [N,40] ----
    lin_kernel<64, 40><<<grid((long)N * 10, BLK), BLK, 0, stream>>>(buf_h, W3, b3, buf_s1, N);

    // ---- layer 3: out = log_softmax(agg(S1)) [full-row] ----
    agg_lsm_kernel<<<aggBlocks, BLK, 0, stream>>>(
        (const float4*)buf_s1, rowptr, epack, (float4*)d_out, N);
}

// Round 14
// 351.006 us; speedup vs baseline: 1.4699x; 1.4699x over previous
//
#include <hip/hip_runtime.h>
#include <hip/hip_bf16.h>
#include <math.h>

// ---------------------------------------------------------------------------
// RESKnorm GCN, CSR-based (no float atomics).
//   R12 structure (best: 362us) + bf16 message matrices S1/S2 (R14):
//   - R13 lesson: agg cost = total gather footprint x 8 XCDs of HBM fetch;
//     panelizing multiplied traffic. Shrink the footprint instead.
//   - S1/S2 feed GroupNorm(2ch groups): d*rsqrt(d^2+eps) saturates to +-1,
//     so bf16 rounding of the agg input is annihilated -> safe (R4 failed
//     because it also bf16'd the GN-free layers 0 and 3; those stay f32).
//   CSR: histogram + 2-dispatch scan + per-node-cursor fill FUSED with lin0
//   (16KB half-column W tiles). lin1/2/3 fused into agg epilogues via
//   wave-private LDS hrow (no end barrier). Waves retire independently.
// N=50000, E=800000, NFEAT=128, NHID=64, NCLASS=40, GROUPS=32 (2 ch/group)
// ---------------------------------------------------------------------------

#define EPS 1e-5f
#define SCAN_BLK 256

// ---- bf16 pack/unpack (RNE); uint = 2 ch, lo = even ch ----
__device__ inline unsigned pack_bf162(float a, float b) {
    union { float f; unsigned u; } ua, ub;
    ua.f = a; ub.f = b;
    unsigned x = ua.u + (0x7fffu + ((ua.u >> 16) & 1u));
    unsigned y = ub.u + (0x7fffu + ((ub.u >> 16) & 1u));
    return (x >> 16) | (y & 0xffff0000u);
}
__device__ inline float bf_lo(unsigned u) {
    union { unsigned u; float f; } c; c.u = u << 16; return c.f;
}
__device__ inline float bf_hi(unsigned u) {
    union { unsigned u; float f; } c; c.u = u & 0xffff0000u; return c.f;
}

// ---------------- CSR build ----------------
__global__ void count_kernel(const int* __restrict__ tgt, int* __restrict__ cnt,
                             int E) {
    int e = blockIdx.x * blockDim.x + threadIdx.x;
    if (e < E) atomicAdd(&cnt[tgt[e]], 1);
}

__global__ void scan_p1(const int* __restrict__ cnt, int* __restrict__ bsum,
                        int n) {
    __shared__ int lds[SCAN_BLK];
    int i = blockIdx.x * SCAN_BLK + threadIdx.x;
    lds[threadIdx.x] = (i < n) ? cnt[i] : 0;
    __syncthreads();
    for (int off = SCAN_BLK / 2; off; off >>= 1) {
        if (threadIdx.x < off) lds[threadIdx.x] += lds[threadIdx.x + off];
        __syncthreads();
    }
    if (threadIdx.x == 0) bsum[blockIdx.x] = lds[0];
}

__global__ void scan_p23(const int* __restrict__ cnt, const int* __restrict__ bsum,
                         int* __restrict__ rowptr, int* __restrict__ cursor,
                         int n) {
    __shared__ int lds[SCAN_BLK];
    __shared__ int boff_s;
    int p = 0;
    for (int i = threadIdx.x; i < (int)blockIdx.x; i += SCAN_BLK) p += bsum[i];
    lds[threadIdx.x] = p;
    __syncthreads();
    for (int off = SCAN_BLK / 2; off; off >>= 1) {
        if (threadIdx.x < off) lds[threadIdx.x] += lds[threadIdx.x + off];
        __syncthreads();
    }
    if (threadIdx.x == 0) boff_s = lds[0];
    __syncthreads();
    int boff = boff_s;
    __syncthreads();
    int i = blockIdx.x * SCAN_BLK + threadIdx.x;
    int v = (i < n) ? cnt[i] : 0;
    lds[threadIdx.x] = v;
    __syncthreads();
    for (int off = 1; off < SCAN_BLK; off <<= 1) {
        int t = (threadIdx.x >= off) ? lds[threadIdx.x - off] : 0;
        __syncthreads();
        lds[threadIdx.x] += t;
        __syncthreads();
    }
    int excl = boff + lds[threadIdx.x] - v;
    if (i < n) {
        rowptr[i] = excl;
        cursor[i] = excl;
        if (i == n - 1) rowptr[n] = excl + v;
    }
}

// ---------------- fused fill + lin0 (half-column 16KB W tiles) -------------
__global__ void fill_lin0_kernel(const int* __restrict__ src,
                                 const int* __restrict__ tgt,
                                 const float* __restrict__ mv,
                                 int* __restrict__ cursor,
                                 long long* __restrict__ ep, int E,
                                 const float* __restrict__ X,
                                 const float4* __restrict__ W4,   // [128*16]
                                 const float4* __restrict__ B4,   // [16]
                                 float4* __restrict__ S4out, int n,
                                 int fillBlocks, int halfBlocks) {
    __shared__ float4 Wl[128 * 8];
    __shared__ float4 Bl8[8];
    if (blockIdx.x < (unsigned)fillBlocks) {
        int e = blockIdx.x * blockDim.x + threadIdx.x;
        if (e >= E) return;
        int pos = atomicAdd(&cursor[tgt[e]], 1);
        long long v = (long long)(unsigned)src[e] |
                      ((long long)__float_as_int(mv[e]) << 32);
        ep[pos] = v;
        return;
    }
    int t = blockIdx.x - fillBlocks;
    int half = (t >= halfBlocks) ? 1 : 0;
    int bi = t - half * halfBlocks;
    for (int i = threadIdx.x; i < 128 * 8; i += blockDim.x)
        Wl[i] = W4[(i >> 3) * 16 + half * 8 + (i & 7)];
    if (threadIdx.x < 8) Bl8[threadIdx.x] = B4[half * 8 + threadIdx.x];
    __syncthreads();
    int idx = bi * blockDim.x + threadIdx.x;
    if (idx >= n * 8) return;
    int row = idx >> 3;
    int c8 = idx & 7;
    const float* xr = X + (long)row * 128;
    float4 acc = Bl8[c8];
#pragma unroll 8
    for (int k = 0; k < 128; ++k) {
        float xv = xr[k];
        float4 w = Wl[k * 8 + c8];
        acc.x = fmaf(xv, w.x, acc.x);
        acc.y = fmaf(xv, w.y, acc.y);
        acc.z = fmaf(xv, w.z, acc.z);
        acc.w = fmaf(xv, w.w, acc.w);
    }
    S4out[(long)row * 16 + half * 8 + c8] = acc;
}

// ---------------- aggregation cores ----------------
#define FMA4(A, V, W4)                                                        \
    A.x = fmaf(V.x, W4, A.x); A.y = fmaf(V.y, W4, A.y);                       \
    A.z = fmaf(V.z, W4, A.z); A.w = fmaf(V.w, W4, A.w);

// f32 gather: lane sub loads float4 (16B) of the source row; stride R4 float4s
#define AGG4_BODY(R4)                                                         \
    int beg = rowptr[wid], end = rowptr[wid + 1];                             \
    float4 a0 = make_float4(0.f, 0.f, 0.f, 0.f), a1 = a0, a2 = a0, a3 = a0;   \
    int j = beg;                                                              \
    for (; j + 16 <= end; j += 16) {                                          \
        long long p0 = ep[j + q], p1 = ep[j + 4 + q];                         \
        long long p2 = ep[j + 8 + q], p3 = ep[j + 12 + q];                    \
        float4 v0 = S4[(long)(int)(unsigned)p0 * R4 + sub];                   \
        float4 v1 = S4[(long)(int)(unsigned)p1 * R4 + sub];                   \
        float4 v2 = S4[(long)(int)(unsigned)p2 * R4 + sub];                   \
        float4 v3 = S4[(long)(int)(unsigned)p3 * R4 + sub];                   \
        float w0 = __int_as_float((int)(p0 >> 32));                           \
        float w1 = __int_as_float((int)(p1 >> 32));                           \
        float w2 = __int_as_float((int)(p2 >> 32));                           \
        float w3 = __int_as_float((int)(p3 >> 32));                           \
        FMA4(a0, v0, w0) FMA4(a1, v1, w1) FMA4(a2, v2, w2) FMA4(a3, v3, w3)   \
    }                                                                         \
    for (; j + 4 <= end; j += 4) {                                            \
        long long p0 = ep[j + q];                                             \
        float4 v0 = S4[(long)(int)(unsigned)p0 * R4 + sub];                   \
        float w0 = __int_as_float((int)(p0 >> 32));                           \
        FMA4(a0, v0, w0)                                                      \
    }                                                                         \
    if (j < end) {                                                            \
        int eidx = j + q;                                                     \
        long long p0 = ep[(eidx < end) ? eidx : (end - 1)];                   \
        float4 v0 = S4[(long)(int)(unsigned)p0 * R4 + sub];                   \
        float w0 = (eidx < end) ? __int_as_float((int)(p0 >> 32)) : 0.f;      \
        FMA4(a0, v0, w0)                                                      \
    }                                                                         \
    float4 acc;                                                               \
    acc.x = (a0.x + a1.x) + (a2.x + a3.x);                                    \
    acc.y = (a0.y + a1.y) + (a2.y + a3.y);                                    \
    acc.z = (a0.z + a1.z) + (a2.z + a3.z);                                    \
    acc.w = (a0.w + a1.w) + (a2.w + a3.w);                                    \
    acc.x += __shfl_xor(acc.x, 16); acc.y += __shfl_xor(acc.y, 16);           \
    acc.z += __shfl_xor(acc.z, 16); acc.w += __shfl_xor(acc.w, 16);           \
    acc.x += __shfl_xor(acc.x, 32); acc.y += __shfl_xor(acc.y, 32);           \
    acc.z += __shfl_xor(acc.z, 32); acc.w += __shfl_xor(acc.w, 32);

#define BF_FMA(A, U, WV)                                                      \
    A.x = fmaf(bf_lo(U.x), WV, A.x); A.y = fmaf(bf_hi(U.x), WV, A.y);         \
    A.z = fmaf(bf_lo(U.y), WV, A.z); A.w = fmaf(bf_hi(U.y), WV, A.w);

// bf16 gather: lane sub loads uint2 (8B = 4 ch); row stride 16 uint2 (128B)
#define AGG4B_BODY()                                                          \
    int beg = rowptr[wid], end = rowptr[wid + 1];                             \
    float4 a0 = make_float4(0.f, 0.f, 0.f, 0.f), a1 = a0, a2 = a0, a3 = a0;   \
    int j = beg;                                                              \
    for (; j + 16 <= end; j += 16) {                                          \
        long long p0 = ep[j + q], p1 = ep[j + 4 + q];                         \
        long long p2 = ep[j + 8 + q], p3 = ep[j + 12 + q];                    \
        uint2 u0 = Sb[(long)(int)(unsigned)p0 * 16 + sub];                    \
        uint2 u1 = Sb[(long)(int)(unsigned)p1 * 16 + sub];                    \
        uint2 u2 = Sb[(long)(int)(unsigned)p2 * 16 + sub];                    \
        uint2 u3 = Sb[(long)(int)(unsigned)p3 * 16 + sub];                    \
        float w0 = __int_as_float((int)(p0 >> 32));                           \
        float w1 = __int_as_float((int)(p1 >> 32));                           \
        float w2 = __int_as_float((int)(p2 >> 32));                           \
        float w3 = __int_as_float((int)(p3 >> 32));                           \
        BF_FMA(a0, u0, w0) BF_FMA(a1, u1, w1)                                 \
        BF_FMA(a2, u2, w2) BF_FMA(a3, u3, w3)                                 \
    }                                                                         \
    for (; j + 4 <= end; j += 4) {                                            \
        long long p0 = ep[j + q];                                             \
        uint2 u0 = Sb[(long)(int)(unsigned)p0 * 16 + sub];                    \
        float w0 = __int_as_float((int)(p0 >> 32));                           \
        BF_FMA(a0, u0, w0)                                                    \
    }                                                                         \
    if (j < end) {                                                            \
        int eidx = j + q;                                                     \
        long long p0 = ep[(eidx < end) ? eidx : (end - 1)];                   \
        uint2 u0 = Sb[(long)(int)(unsigned)p0 * 16 + sub];                    \
        float w0 = (eidx < end) ? __int_as_float((int)(p0 >> 32)) : 0.f;      \
        BF_FMA(a0, u0, w0)                                                    \
    }                                                                         \
    float4 acc;                                                               \
    acc.x = (a0.x + a1.x) + (a2.x + a3.x);                                    \
    acc.y = (a0.y + a1.y) + (a2.y + a3.y);                                    \
    acc.z = (a0.z + a1.z) + (a2.z + a3.z);                                    \
    acc.w = (a0.w + a1.w) + (a2.w + a3.w);                                    \
    acc.x += __shfl_xor(acc.x, 16); acc.y += __shfl_xor(acc.y, 16);           \
    acc.z += __shfl_xor(acc.z, 16); acc.w += __shfl_xor(acc.w, 16);           \
    acc.x += __shfl_xor(acc.x, 32); acc.y += __shfl_xor(acc.y, 32);           \
    acc.z += __shfl_xor(acc.z, 32); acc.w += __shfl_xor(acc.w, 32);

// lin tail core: o = (hrow[w] @ W)[4sub..4sub+4); quarters split k
#define LIN_TAIL_CORE(C4OUT)                                                  \
    float4 o = make_float4(0.f, 0.f, 0.f, 0.f);                               \
    {                                                                         \
        const float* hr = hrow[w];                                            \
        _Pragma("unroll")                                                     \
        for (int kk = 0; kk < 16; ++kk) {                                     \
            float hv = hr[16 * q + kk];                                       \
            float4 wv = Wl[(16 * q + kk) * C4OUT + sub];                      \
            FMA4(o, wv, hv)                                                   \
        }                                                                     \
        o.x += __shfl_xor(o.x, 16); o.y += __shfl_xor(o.y, 16);               \
        o.z += __shfl_xor(o.z, 16); o.w += __shfl_xor(o.w, 16);               \
        o.x += __shfl_xor(o.x, 32); o.y += __shfl_xor(o.y, 32);               \
        o.z += __shfl_xor(o.z, 32); o.w += __shfl_xor(o.w, 32);               \
    }

// layer 0: h = relu(agg_f32(S0)); write H; S1(bf16) = h@W1+b1
__global__ void agg_relu_lin_kernel(const float4* __restrict__ S4,
                                    const int* __restrict__ rowptr,
                                    const long long* __restrict__ ep,
                                    const float4* __restrict__ W4,  // [64*16]
                                    const float4* __restrict__ B4,  // [16]
                                    float4* __restrict__ H4,
                                    uint2* __restrict__ SbOut, int n) {
    __shared__ float4 Wl[64 * 16];
    __shared__ float4 Bl[16];
    __shared__ float hrow[4][64];
    for (int i = threadIdx.x; i < 64 * 16; i += blockDim.x) Wl[i] = W4[i];
    if (threadIdx.x < 16) Bl[threadIdx.x] = B4[threadIdx.x];
    __syncthreads();   // only barrier: W-tile staging
    int wid = (blockIdx.x * blockDim.x + threadIdx.x) >> 6;
    int lane = threadIdx.x & 63;
    int q = lane >> 4, sub = lane & 15;
    int w = threadIdx.x >> 6;
    if (wid >= n) return;
    AGG4_BODY(16)
    if (q == 0) {
        float4 h = make_float4(fmaxf(acc.x, 0.f), fmaxf(acc.y, 0.f),
                               fmaxf(acc.z, 0.f), fmaxf(acc.w, 0.f));
        H4[(long)wid * 16 + sub] = h;
        ((float4*)hrow[w])[sub] = h;
    }
    LIN_TAIL_CORE(16)
    if (q == 0) {
        float4 b = Bl[sub];
        o.x += b.x; o.y += b.y; o.z += b.z; o.w += b.w;
        SbOut[(long)wid * 16 + sub] =
            make_uint2(pack_bf162(o.x, o.y), pack_bf162(o.z, o.w));
    }
}

// layer 1: h = gn(relu(agg_bf16(S1))) + H; S2(bf16) = h@W2+b2
__global__ void agg_gn_lin_b2b_kernel(const uint2* __restrict__ Sb,
                                      const int* __restrict__ rowptr,
                                      const long long* __restrict__ ep,
                                      const float4* __restrict__ gamma,
                                      const float4* __restrict__ beta,
                                      const float4* __restrict__ W4,  // [64*16]
                                      const float4* __restrict__ B4,  // [16]
                                      float4* __restrict__ H4,
                                      uint2* __restrict__ SbOut, int n) {
    __shared__ float4 Wl[64 * 16];
    __shared__ float4 Bl[16];
    __shared__ float hrow[4][64];
    for (int i = threadIdx.x; i < 64 * 16; i += blockDim.x) Wl[i] = W4[i];
    if (threadIdx.x < 16) Bl[threadIdx.x] = B4[threadIdx.x];
    __syncthreads();
    int wid = (blockIdx.x * blockDim.x + threadIdx.x) >> 6;
    int lane = threadIdx.x & 63;
    int q = lane >> 4, sub = lane & 15;
    int w = threadIdx.x >> 6;
    if (wid >= n) return;
    AGG4B_BODY()
    if (q == 0) {
        float p0 = fmaxf(acc.x, 0.f), p1 = fmaxf(acc.y, 0.f);
        float p2 = fmaxf(acc.z, 0.f), p3 = fmaxf(acc.w, 0.f);
        float dA = 0.5f * (p0 - p1);
        float dB = 0.5f * (p2 - p3);
        float rsA = rsqrtf(dA * dA + EPS);
        float rsB = rsqrtf(dB * dB + EPS);
        float4 g = gamma[sub], be = beta[sub];
        long off = (long)wid * 16 + sub;
        float4 h = H4[off];
        h.x += dA * rsA * g.x + be.x;
        h.y += -dA * rsA * g.y + be.y;
        h.z += dB * rsB * g.z + be.z;
        h.w += -dB * rsB * g.w + be.w;
        H4[off] = h;
        ((float4*)hrow[w])[sub] = h;
    }
    LIN_TAIL_CORE(16)
    if (q == 0) {
        float4 b = Bl[sub];
        o.x += b.x; o.y += b.y; o.z += b.z; o.w += b.w;
        SbOut[(long)wid * 16 + sub] =
            make_uint2(pack_bf162(o.x, o.y), pack_bf162(o.z, o.w));
    }
}

// layer 2: h = gn(relu(agg_bf16(S2))) + H; S3(f32,[N,40]) = h@W3+b3
__global__ void agg_gn_lin_b2f_kernel(const uint2* __restrict__ Sb,
                                      const int* __restrict__ rowptr,
                                      const long long* __restrict__ ep,
                                      const float4* __restrict__ gamma,
                                      const float4* __restrict__ beta,
                                      const float4* __restrict__ W4,  // [64*10]
                                      const float4* __restrict__ B4,  // [10]
                                      float4* __restrict__ H4,
                                      float4* __restrict__ S4out, int n) {
    __shared__ float4 Wl[64 * 10];
    __shared__ float4 Bl[10];
    __shared__ float hrow[4][64];
    for (int i = threadIdx.x; i < 64 * 10; i += blockDim.x) Wl[i] = W4[i];
    if (threadIdx.x < 10) Bl[threadIdx.x] = B4[threadIdx.x];
    __syncthreads();
    int wid = (blockIdx.x * blockDim.x + threadIdx.x) >> 6;
    int lane = threadIdx.x & 63;
    int q = lane >> 4, sub = lane & 15;
    int w = threadIdx.x >> 6;
    if (wid >= n) return;
    AGG4B_BODY()
    if (q == 0) {
        float p0 = fmaxf(acc.x, 0.f), p1 = fmaxf(acc.y, 0.f);
        float p2 = fmaxf(acc.z, 0.f), p3 = fmaxf(acc.w, 0.f);
        float dA = 0.5f * (p0 - p1);
        float dB = 0.5f * (p2 - p3);
        float rsA = rsqrtf(dA * dA + EPS);
        float rsB = rsqrtf(dB * dB + EPS);
        float4 g = gamma[sub], be = beta[sub];
        long off = (long)wid * 16 + sub;
        float4 h = H4[off];
        h.x += dA * rsA * g.x + be.x;
        h.y += -dA * rsA * g.y + be.y;
        h.z += dB * rsB * g.z + be.z;
        h.w += -dB * rsB * g.w + be.w;
        H4[off] = h;
        ((float4*)hrow[w])[sub] = h;
    }
    if (sub < 10) {
        LIN_TAIL_CORE(10)
        if (q == 0) {
            float4 b = Bl[sub];
            o.x += b.x; o.y += b.y; o.z += b.z; o.w += b.w;
            S4out[(long)wid * 10 + sub] = o;
        }
    }
}

// layer 3: log_softmax(agg_f32(S3)) over 40 classes
__global__ void agg_lsm_kernel(const float4* __restrict__ S4,
                               const int* __restrict__ rowptr,
                               const long long* __restrict__ ep,
                               float4* __restrict__ out4, int n) {
    int wid = (blockIdx.x * blockDim.x + threadIdx.x) >> 6;
    int lane = threadIdx.x & 63;
    int q = lane >> 4;
    int sub0 = lane & 15;
    int sub = (sub0 < 10) ? sub0 : 9;  // clamp: in-bounds dup loads, ignored
    if (wid >= n) return;
    AGG4_BODY(10)
    bool valid = sub0 < 10;
    float m = valid ? fmaxf(fmaxf(acc.x, acc.y), fmaxf(acc.z, acc.w)) : -INFINITY;
#pragma unroll
    for (int mk = 8; mk; mk >>= 1) m = fmaxf(m, __shfl_xor(m, mk));
    float ex = valid ? (expf(acc.x - m) + expf(acc.y - m) +
                        expf(acc.z - m) + expf(acc.w - m)) : 0.f;
#pragma unroll
    for (int mk = 8; mk; mk >>= 1) ex += __shfl_xor(ex, mk);
    float l = m + logf(ex);
    if (q == 0 && valid)
        out4[(long)wid * 10 + sub0] =
            make_float4(acc.x - l, acc.y - l, acc.z - l, acc.w - l);
}

extern "C" void kernel_launch(void* const* d_in, const int* in_sizes, int n_in,
                              void* d_out, int out_size, void* d_ws,
                              size_t ws_size, hipStream_t stream) {
    const float* x = (const float*)d_in[0];
    const int* src = (const int*)d_in[1];
    const int* tgt = (const int*)d_in[2];
    const float* mv = (const float*)d_in[3];
    const float* W0 = (const float*)d_in[4];
    const float* b0 = (const float*)d_in[5];
    const float* W1 = (const float*)d_in[6];
    const float* b1 = (const float*)d_in[7];
    const float* W2 = (const float*)d_in[8];
    const float* b2 = (const float*)d_in[9];
    const float* W3 = (const float*)d_in[10];
    const float* b3 = (const float*)d_in[11];
    const float* g1 = (const float*)d_in[12];
    const float* beta1 = (const float*)d_in[13];
    const float* g2 = (const float*)d_in[14];
    const float* beta2 = (const float*)d_in[15];

    const int N = in_sizes[0] / 128;
    const int E = in_sizes[1];

    float* buf_s0 = (float*)d_ws;               // [N,64] f32 S0; later S3 [N,40]
    float* buf_h = buf_s0 + (size_t)N * 64;     // [N,64] f32 h / residual
    unsigned* buf_sb1 = (unsigned*)(buf_h + (size_t)N * 64);  // [N*32] bf16 S1
    unsigned* buf_sb2 = buf_sb1 + (size_t)N * 32;             // [N*32] bf16 S2
    int* rowptr = (int*)(buf_sb2 + (size_t)N * 32);  // [N+1]
    int* cursor = rowptr + (N + 1);             // [N]
    int* cnt = cursor + N;                      // [N]
    int* bsum = cnt + N;                        // [<=1024]
    long long* epack = (long long*)(((uintptr_t)(bsum + 1024) + 15) & ~(uintptr_t)15);

    const int BLK = 256;
    auto grid = [](long total, int blk) { return (int)((total + blk - 1) / blk); };
    const int scanBlocks = grid(N, SCAN_BLK);
    const int fillBlocks = grid(E, BLK);
    const int halfBlocks = grid((long)N * 8, BLK);

    // ---- CSR build ----
    hipMemsetAsync(cnt, 0, (size_t)N * sizeof(int), stream);
    count_kernel<<<grid(E, BLK), BLK, 0, stream>>>(tgt, cnt, E);
    scan_p1<<<scanBlocks, SCAN_BLK, 0, stream>>>(cnt, bsum, N);
    scan_p23<<<scanBlocks, SCAN_BLK, 0, stream>>>(cnt, bsum, rowptr, cursor, N);

    // ---- fused: CSR fill + layer-0 linear (half-tile LDS) -> S0 (f32) ----
    fill_lin0_kernel<<<fillBlocks + 2 * halfBlocks, BLK, 0, stream>>>(
        src, tgt, mv, cursor, epack, E, x, (const float4*)W0, (const float4*)b0,
        (float4*)buf_s0, N, fillBlocks, halfBlocks);

    const int aggBlocks = grid((long)N * 64, BLK);  // 4 waves (nodes) per block

    // ---- layer 0: agg f32 S0 -> H; S1 = bf16(h@W1+b1) ----
    agg_relu_lin_kernel<<<aggBlocks, BLK, 0, stream>>>(
        (const float4*)buf_s0, rowptr, epack, (const float4*)W1,
        (const float4*)b1, (float4*)buf_h, (uint2*)buf_sb1, N);

    // ---- layer 1: agg bf16 S1 -> H; S2 = bf16(h@W2+b2) ----
    agg_gn_lin_b2b_kernel<<<aggBlocks, BLK, 0, stream>>>(
        (const uint2*)buf_sb1, rowptr, epack, (const float4*)g1,
        (const float4*)beta1, (const float4*)W2, (const float4*)b2,
        (float4*)buf_h, (uint2*)buf_sb2, N);

    // ---- layer 2: agg bf16 S2 -> H; S3 = f32(h@W3+b3) [N,40], aliases S0 ----
    agg_gn_lin_b2f_kernel<<<aggBlocks, BLK, 0, stream>>>(
        (const uint2*)buf_sb2, rowptr, epack, (const float4*)g2,
        (const float4*)beta2, (const float4*)W3, (const float4*)b3,
        (float4*)buf_h, (float4*)buf_s0, N);

    // ---- layer 3: out = log_softmax(agg f32 S3) ----
    agg_lsm_kernel<<<aggBlocks, BLK, 0, stream>>>(
        (const float4*)buf_s0, rowptr, epack, (float4*)d_out, N);
}

// Round 15
// 345.545 us; speedup vs baseline: 1.4931x; 1.0158x over previous
//
#include <hip/hip_runtime.h>
#include <hip/hip_bf16.h>
#include <hip/hip_fp16.h>
#include <math.h>

// ---------------------------------------------------------------------------
// RESKnorm GCN, CSR-based (no float atomics).
//   R14 structure + ALL message matrices in FP16 (R15):
//   - agg dispatches sit at the ~1.65 TB/s random-gather HBM ceiling (R13),
//     so cost = gather footprint x 8 XCDs. fp16 halves S0/S3 footprints vs
//     f32 AND has 8x less rounding error than bf16 (11-bit vs 8-bit mantissa)
//     at identical traffic -> absmax improves vs R14 while getting faster.
//     Value ranges (|logits|<~150) are far inside fp16 range.
//   - Accumulation, H, residual, GN math all stay f32.
//   CSR: histogram + 2-dispatch scan + per-node-cursor fill FUSED with lin0
//   (16KB half-column W tiles). lin1/2/3 fused into agg epilogues via
//   wave-private LDS hrow (no end barrier). Waves retire independently.
// N=50000, E=800000, NFEAT=128, NHID=64, NCLASS=40, GROUPS=32 (2 ch/group)
// ---------------------------------------------------------------------------

#define EPS 1e-5f
#define SCAN_BLK 256

// ---- fp16 pack/unpack: uint = 2 ch (lo = even ch), uint2 = 4 ch ----
__device__ inline unsigned pack_h2(float a, float b) {
    __half2 h = __floats2half2_rn(a, b);
    return *(unsigned*)&h;
}
__device__ inline float2 unpack_h2(unsigned u) {
    __half2 h = *(__half2*)&u;
    return __half22float2(h);
}

// ---------------- CSR build ----------------
__global__ void count_kernel(const int* __restrict__ tgt, int* __restrict__ cnt,
                             int E) {
    int e = blockIdx.x * blockDim.x + threadIdx.x;
    if (e < E) atomicAdd(&cnt[tgt[e]], 1);
}

__global__ void scan_p1(const int* __restrict__ cnt, int* __restrict__ bsum,
                        int n) {
    __shared__ int lds[SCAN_BLK];
    int i = blockIdx.x * SCAN_BLK + threadIdx.x;
    lds[threadIdx.x] = (i < n) ? cnt[i] : 0;
    __syncthreads();
    for (int off = SCAN_BLK / 2; off; off >>= 1) {
        if (threadIdx.x < off) lds[threadIdx.x] += lds[threadIdx.x + off];
        __syncthreads();
    }
    if (threadIdx.x == 0) bsum[blockIdx.x] = lds[0];
}

__global__ void scan_p23(const int* __restrict__ cnt, const int* __restrict__ bsum,
                         int* __restrict__ rowptr, int* __restrict__ cursor,
                         int n) {
    __shared__ int lds[SCAN_BLK];
    __shared__ int boff_s;
    int p = 0;
    for (int i = threadIdx.x; i < (int)blockIdx.x; i += SCAN_BLK) p += bsum[i];
    lds[threadIdx.x] = p;
    __syncthreads();
    for (int off = SCAN_BLK / 2; off; off >>= 1) {
        if (threadIdx.x < off) lds[threadIdx.x] += lds[threadIdx.x + off];
        __syncthreads();
    }
    if (threadIdx.x == 0) boff_s = lds[0];
    __syncthreads();
    int boff = boff_s;
    __syncthreads();
    int i = blockIdx.x * SCAN_BLK + threadIdx.x;
    int v = (i < n) ? cnt[i] : 0;
    lds[threadIdx.x] = v;
    __syncthreads();
    for (int off = 1; off < SCAN_BLK; off <<= 1) {
        int t = (threadIdx.x >= off) ? lds[threadIdx.x - off] : 0;
        __syncthreads();
        lds[threadIdx.x] += t;
        __syncthreads();
    }
    int excl = boff + lds[threadIdx.x] - v;
    if (i < n) {
        rowptr[i] = excl;
        cursor[i] = excl;
        if (i == n - 1) rowptr[n] = excl + v;
    }
}

// ---------------- fused fill + lin0 (half-column 16KB W tiles) -------------
// fill blocks: scatter packed edge {src, wbits}; lin0 blocks: S0(fp16)=x@W0+b0
__global__ void fill_lin0_kernel(const int* __restrict__ src,
                                 const int* __restrict__ tgt,
                                 const float* __restrict__ mv,
                                 int* __restrict__ cursor,
                                 long long* __restrict__ ep, int E,
                                 const float* __restrict__ X,
                                 const float4* __restrict__ W4,   // [128*16]
                                 const float4* __restrict__ B4,   // [16]
                                 uint2* __restrict__ ShOut, int n,
                                 int fillBlocks, int halfBlocks) {
    __shared__ float4 Wl[128 * 8];
    __shared__ float4 Bl8[8];
    if (blockIdx.x < (unsigned)fillBlocks) {
        int e = blockIdx.x * blockDim.x + threadIdx.x;
        if (e >= E) return;
        int pos = atomicAdd(&cursor[tgt[e]], 1);
        long long v = (long long)(unsigned)src[e] |
                      ((long long)__float_as_int(mv[e]) << 32);
        ep[pos] = v;
        return;
    }
    int t = blockIdx.x - fillBlocks;
    int half = (t >= halfBlocks) ? 1 : 0;
    int bi = t - half * halfBlocks;
    for (int i = threadIdx.x; i < 128 * 8; i += blockDim.x)
        Wl[i] = W4[(i >> 3) * 16 + half * 8 + (i & 7)];
    if (threadIdx.x < 8) Bl8[threadIdx.x] = B4[half * 8 + threadIdx.x];
    __syncthreads();
    int idx = bi * blockDim.x + threadIdx.x;
    if (idx >= n * 8) return;
    int row = idx >> 3;
    int c8 = idx & 7;
    const float* xr = X + (long)row * 128;
    float4 acc = Bl8[c8];
#pragma unroll 8
    for (int k = 0; k < 128; ++k) {
        float xv = xr[k];
        float4 w = Wl[k * 8 + c8];
        acc.x = fmaf(xv, w.x, acc.x);
        acc.y = fmaf(xv, w.y, acc.y);
        acc.z = fmaf(xv, w.z, acc.z);
        acc.w = fmaf(xv, w.w, acc.w);
    }
    ShOut[(long)row * 16 + half * 8 + c8] =
        make_uint2(pack_h2(acc.x, acc.y), pack_h2(acc.z, acc.w));
}

// ---------------- aggregation core (fp16 gather, f32 accumulate) -----------
#define FMA4(A, V, W4)                                                        \
    A.x = fmaf(V.x, W4, A.x); A.y = fmaf(V.y, W4, A.y);                       \
    A.z = fmaf(V.z, W4, A.z); A.w = fmaf(V.w, W4, A.w);

#define HF_FMA(A, U, WV) {                                                    \
    float2 _lo = unpack_h2(U.x), _hi = unpack_h2(U.y);                        \
    A.x = fmaf(_lo.x, WV, A.x); A.y = fmaf(_lo.y, WV, A.y);                   \
    A.z = fmaf(_hi.x, WV, A.z); A.w = fmaf(_hi.y, WV, A.w); }

// lane sub loads uint2 (8B = 4 fp16 ch) of the source row; stride R2 uint2s
#define AGG4H_BODY(R2)                                                        \
    int beg = rowptr[wid], end = rowptr[wid + 1];                             \
    float4 a0 = make_float4(0.f, 0.f, 0.f, 0.f), a1 = a0, a2 = a0, a3 = a0;   \
    int j = beg;                                                              \
    for (; j + 16 <= end; j += 16) {                                          \
        long long p0 = ep[j + q], p1 = ep[j + 4 + q];                         \
        long long p2 = ep[j + 8 + q], p3 = ep[j + 12 + q];                    \
        uint2 u0 = Sh[(long)(int)(unsigned)p0 * R2 + sub];                    \
        uint2 u1 = Sh[(long)(int)(unsigned)p1 * R2 + sub];                    \
        uint2 u2 = Sh[(long)(int)(unsigned)p2 * R2 + sub];                    \
        uint2 u3 = Sh[(long)(int)(unsigned)p3 * R2 + sub];                    \
        float w0 = __int_as_float((int)(p0 >> 32));                           \
        float w1 = __int_as_float((int)(p1 >> 32));                           \
        float w2 = __int_as_float((int)(p2 >> 32));                           \
        float w3 = __int_as_float((int)(p3 >> 32));                           \
        HF_FMA(a0, u0, w0) HF_FMA(a1, u1, w1)                                 \
        HF_FMA(a2, u2, w2) HF_FMA(a3, u3, w3)                                 \
    }                                                                         \
    for (; j + 4 <= end; j += 4) {                                            \
        long long p0 = ep[j + q];                                             \
        uint2 u0 = Sh[(long)(int)(unsigned)p0 * R2 + sub];                    \
        float w0 = __int_as_float((int)(p0 >> 32));                           \
        HF_FMA(a0, u0, w0)                                                    \
    }                                                                         \
    if (j < end) {                                                            \
        int eidx = j + q;                                                     \
        long long p0 = ep[(eidx < end) ? eidx : (end - 1)];                   \
        uint2 u0 = Sh[(long)(int)(unsigned)p0 * R2 + sub];                    \
        float w0 = (eidx < end) ? __int_as_float((int)(p0 >> 32)) : 0.f;      \
        HF_FMA(a0, u0, w0)                                                    \
    }                                                                         \
    float4 acc;                                                               \
    acc.x = (a0.x + a1.x) + (a2.x + a3.x);                                    \
    acc.y = (a0.y + a1.y) + (a2.y + a3.y);                                    \
    acc.z = (a0.z + a1.z) + (a2.z + a3.z);                                    \
    acc.w = (a0.w + a1.w) + (a2.w + a3.w);                                    \
    acc.x += __shfl_xor(acc.x, 16); acc.y += __shfl_xor(acc.y, 16);           \
    acc.z += __shfl_xor(acc.z, 16); acc.w += __shfl_xor(acc.w, 16);           \
    acc.x += __shfl_xor(acc.x, 32); acc.y += __shfl_xor(acc.y, 32);           \
    acc.z += __shfl_xor(acc.z, 32); acc.w += __shfl_xor(acc.w, 32);

// lin tail core: o = (hrow[w] @ W)[4sub..4sub+4); quarters split k
#define LIN_TAIL_CORE(C4OUT)                                                  \
    float4 o = make_float4(0.f, 0.f, 0.f, 0.f);                               \
    {                                                                         \
        const float* hr = hrow[w];                                            \
        _Pragma("unroll")                                                     \
        for (int kk = 0; kk < 16; ++kk) {                                     \
            float hv = hr[16 * q + kk];                                       \
            float4 wv = Wl[(16 * q + kk) * C4OUT + sub];                      \
            FMA4(o, wv, hv)                                                   \
        }                                                                     \
        o.x += __shfl_xor(o.x, 16); o.y += __shfl_xor(o.y, 16);               \
        o.z += __shfl_xor(o.z, 16); o.w += __shfl_xor(o.w, 16);               \
        o.x += __shfl_xor(o.x, 32); o.y += __shfl_xor(o.y, 32);               \
        o.z += __shfl_xor(o.z, 32); o.w += __shfl_xor(o.w, 32);               \
    }

// layer 0: h = relu(agg(S0)); write H(f32); S1(fp16) = h@W1+b1
__global__ void agg_relu_lin_kernel(const uint2* __restrict__ Sh,
                                    const int* __restrict__ rowptr,
                                    const long long* __restrict__ ep,
                                    const float4* __restrict__ W4,  // [64*16]
                                    const float4* __restrict__ B4,  // [16]
                                    float4* __restrict__ H4,
                                    uint2* __restrict__ ShOut, int n) {
    __shared__ float4 Wl[64 * 16];
    __shared__ float4 Bl[16];
    __shared__ float hrow[4][64];
    for (int i = threadIdx.x; i < 64 * 16; i += blockDim.x) Wl[i] = W4[i];
    if (threadIdx.x < 16) Bl[threadIdx.x] = B4[threadIdx.x];
    __syncthreads();   // only barrier: W-tile staging
    int wid = (blockIdx.x * blockDim.x + threadIdx.x) >> 6;
    int lane = threadIdx.x & 63;
    int q = lane >> 4, sub = lane & 15;
    int w = threadIdx.x >> 6;
    if (wid >= n) return;
    AGG4H_BODY(16)
    if (q == 0) {
        float4 h = make_float4(fmaxf(acc.x, 0.f), fmaxf(acc.y, 0.f),
                               fmaxf(acc.z, 0.f), fmaxf(acc.w, 0.f));
        H4[(long)wid * 16 + sub] = h;
        ((float4*)hrow[w])[sub] = h;
    }
    LIN_TAIL_CORE(16)
    if (q == 0) {
        float4 b = Bl[sub];
        o.x += b.x; o.y += b.y; o.z += b.z; o.w += b.w;
        ShOut[(long)wid * 16 + sub] =
            make_uint2(pack_h2(o.x, o.y), pack_h2(o.z, o.w));
    }
}

// layers 1-2: h = gn(relu(agg(S))) + H (in-place); S_next(fp16) = h@W+b
// C4OUT=16 (->S2 [N,64]) or 10 (->S3 [N,40])
template <int C4OUT>
__global__ void agg_gn_lin_kernel(const uint2* __restrict__ Sh,
                                  const int* __restrict__ rowptr,
                                  const long long* __restrict__ ep,
                                  const float4* __restrict__ gamma,
                                  const float4* __restrict__ beta,
                                  const float4* __restrict__ W4,  // [64*C4OUT]
                                  const float4* __restrict__ B4,  // [C4OUT]
                                  float4* __restrict__ H4,
                                  uint2* __restrict__ ShOut, int n) {
    __shared__ float4 Wl[64 * C4OUT];
    __shared__ float4 Bl[C4OUT];
    __shared__ float hrow[4][64];
    for (int i = threadIdx.x; i < 64 * C4OUT; i += blockDim.x) Wl[i] = W4[i];
    if (threadIdx.x < C4OUT) Bl[threadIdx.x] = B4[threadIdx.x];
    __syncthreads();
    int wid = (blockIdx.x * blockDim.x + threadIdx.x) >> 6;
    int lane = threadIdx.x & 63;
    int q = lane >> 4, sub = lane & 15;
    int w = threadIdx.x >> 6;
    if (wid >= n) return;
    AGG4H_BODY(16)
    if (q == 0) {
        float p0 = fmaxf(acc.x, 0.f), p1 = fmaxf(acc.y, 0.f);
        float p2 = fmaxf(acc.z, 0.f), p3 = fmaxf(acc.w, 0.f);
        float dA = 0.5f * (p0 - p1);
        float dB = 0.5f * (p2 - p3);
        float rsA = rsqrtf(dA * dA + EPS);
        float rsB = rsqrtf(dB * dB + EPS);
        float4 g = gamma[sub], be = beta[sub];
        long off = (long)wid * 16 + sub;
        float4 h = H4[off];
        h.x += dA * rsA * g.x + be.x;
        h.y += -dA * rsA * g.y + be.y;
        h.z += dB * rsB * g.z + be.z;
        h.w += -dB * rsB * g.w + be.w;
        H4[off] = h;
        ((float4*)hrow[w])[sub] = h;
    }
    if (sub < C4OUT) {
        LIN_TAIL_CORE(C4OUT)
        if (q == 0) {
            float4 b = Bl[sub];
            o.x += b.x; o.y += b.y; o.z += b.z; o.w += b.w;
            ShOut[(long)wid * C4OUT + sub] =
                make_uint2(pack_h2(o.x, o.y), pack_h2(o.z, o.w));
        }
    }
}

// layer 3: log_softmax(agg(S3 fp16 [N,40])) over 40 classes
__global__ void agg_lsm_kernel(const uint2* __restrict__ Sh,
                               const int* __restrict__ rowptr,
                               const long long* __restrict__ ep,
                               float4* __restrict__ out4, int n) {
    int wid = (blockIdx.x * blockDim.x + threadIdx.x) >> 6;
    int lane = threadIdx.x & 63;
    int q = lane >> 4;
    int sub0 = lane & 15;
    int sub = (sub0 < 10) ? sub0 : 9;  // clamp: in-bounds dup loads, ignored
    if (wid >= n) return;
    AGG4H_BODY(10)
    bool valid = sub0 < 10;
    float m = valid ? fmaxf(fmaxf(acc.x, acc.y), fmaxf(acc.z, acc.w)) : -INFINITY;
#pragma unroll
    for (int mk = 8; mk; mk >>= 1) m = fmaxf(m, __shfl_xor(m, mk));
    float ex = valid ? (expf(acc.x - m) + expf(acc.y - m) +
                        expf(acc.z - m) + expf(acc.w - m)) : 0.f;
#pragma unroll
    for (int mk = 8; mk; mk >>= 1) ex += __shfl_xor(ex, mk);
    float l = m + logf(ex);
    if (q == 0 && valid)
        out4[(long)wid * 10 + sub0] =
            make_float4(acc.x - l, acc.y - l, acc.z - l, acc.w - l);
}

extern "C" void kernel_launch(void* const* d_in, const int* in_sizes, int n_in,
                              void* d_out, int out_size, void* d_ws,
                              size_t ws_size, hipStream_t stream) {
    const float* x = (const float*)d_in[0];
    const int* src = (const int*)d_in[1];
    const int* tgt = (const int*)d_in[2];
    const float* mv = (const float*)d_in[3];
    const float* W0 = (const float*)d_in[4];
    const float* b0 = (const float*)d_in[5];
    const float* W1 = (const float*)d_in[6];
    const float* b1 = (const float*)d_in[7];
    const float* W2 = (const float*)d_in[8];
    const float* b2 = (const float*)d_in[9];
    const float* W3 = (const float*)d_in[10];
    const float* b3 = (const float*)d_in[11];
    const float* g1 = (const float*)d_in[12];
    const float* beta1 = (const float*)d_in[13];
    const float* g2 = (const float*)d_in[14];
    const float* beta2 = (const float*)d_in[15];

    const int N = in_sizes[0] / 128;
    const int E = in_sizes[1];

    uint2* buf_sh0 = (uint2*)d_ws;                    // [N*16] fp16 S0; later S3 [N*10]
    float* buf_h = (float*)(buf_sh0 + (size_t)N * 16);  // [N,64] f32 h/residual
    uint2* buf_sh1 = (uint2*)(buf_h + (size_t)N * 64);  // [N*16] fp16 S1
    uint2* buf_sh2 = buf_sh1 + (size_t)N * 16;          // [N*16] fp16 S2
    int* rowptr = (int*)(buf_sh2 + (size_t)N * 16);     // [N+1]
    int* cursor = rowptr + (N + 1);             // [N]
    int* cnt = cursor + N;                      // [N]
    int* bsum = cnt + N;                        // [<=1024]
    long long* epack = (long long*)(((uintptr_t)(bsum + 1024) + 15) & ~(uintptr_t)15);

    const int BLK = 256;
    auto grid = [](long total, int blk) { return (int)((total + blk - 1) / blk); };
    const int scanBlocks = grid(N, SCAN_BLK);
    const int fillBlocks = grid(E, BLK);
    const int halfBlocks = grid((long)N * 8, BLK);

    // ---- CSR build ----
    hipMemsetAsync(cnt, 0, (size_t)N * sizeof(int), stream);
    count_kernel<<<grid(E, BLK), BLK, 0, stream>>>(tgt, cnt, E);
    scan_p1<<<scanBlocks, SCAN_BLK, 0, stream>>>(cnt, bsum, N);
    scan_p23<<<scanBlocks, SCAN_BLK, 0, stream>>>(cnt, bsum, rowptr, cursor, N);

    // ---- fused: CSR fill + layer-0 linear -> S0 (fp16) ----
    fill_lin0_kernel<<<fillBlocks + 2 * halfBlocks, BLK, 0, stream>>>(
        src, tgt, mv, cursor, epack, E, x, (const float4*)W0, (const float4*)b0,
        buf_sh0, N, fillBlocks, halfBlocks);

    const int aggBlocks = grid((long)N * 64, BLK);  // 4 waves (nodes) per block

    // ---- layer 0: agg S0 -> H; S1 = fp16(h@W1+b1) ----
    agg_relu_lin_kernel<<<aggBlocks, BLK, 0, stream>>>(
        buf_sh0, rowptr, epack, (const float4*)W1, (const float4*)b1,
        (float4*)buf_h, buf_sh1, N);

    // ---- layer 1: agg S1 -> H; S2 = fp16(h@W2+b2) ----
    agg_gn_lin_kernel<16><<<aggBlocks, BLK, 0, stream>>>(
        buf_sh1, rowptr, epack, (const float4*)g1, (const float4*)beta1,
        (const float4*)W2, (const float4*)b2, (float4*)buf_h, buf_sh2, N);

    // ---- layer 2: agg S2 -> H; S3 = fp16(h@W3+b3) [N,40], aliases S0 ----
    agg_gn_lin_kernel<10><<<aggBlocks, BLK, 0, stream>>>(
        buf_sh2, rowptr, epack, (const float4*)g2, (const float4*)beta2,
        (const float4*)W3, (const float4*)b3, (float4*)buf_h, buf_sh0, N);

    // ---- layer 3: out = log_softmax(agg S3) ----
    agg_lsm_kernel<<<aggBlocks, BLK, 0, stream>>>(
        buf_sh0, rowptr, epack, (float4*)d_out, N);
}